// Round 1
// baseline (2583.054 us; speedup 1.0000x reference)
//
#include <hip/hip_runtime.h>
#include <math.h>

#define NN 2048
#define FD 512
#define DXF 256
#define BI 16
#define BJ 16
#define JC 4
#define CHK 512
#define TILES (CHK/BJ)

// ---------- layernorm rows of h ----------
__global__ void ln_rows_k(const float* __restrict__ h, const float* __restrict__ g,
                          const float* __restrict__ b, float* __restrict__ out) {
  int r = blockIdx.x, t = threadIdx.x;
  float2 v = ((const float2*)(h + (size_t)r * FD))[t];
  float2 w = make_float2(v.x + v.y, v.x * v.x + v.y * v.y);
#pragma unroll
  for (int o = 32; o > 0; o >>= 1) { w.x += __shfl_xor(w.x, o); w.y += __shfl_xor(w.y, o); }
  __shared__ float red[4][2];
  if ((t & 63) == 0) { red[t >> 6][0] = w.x; red[t >> 6][1] = w.y; }
  __syncthreads();
  float S  = (red[0][0] + red[1][0]) + (red[2][0] + red[3][0]);
  float SQ = (red[0][1] + red[1][1]) + (red[2][1] + red[3][1]);
  float mean = S * (1.f / FD);
  float var  = SQ * (1.f / FD) - mean * mean;
  float rs = rsqrtf(var + 1e-5f);
  float2 gg = ((const float2*)g)[t], bb = ((const float2*)b)[t];
  float2 o2;
  o2.x = (v.x - mean) * rs * gg.x + bb.x;
  o2.y = (v.y - mean) * rs * gg.y + bb.y;
  ((float2*)(out + (size_t)r * FD))[t] = o2;
}

// ---------- l1 normalize rows of x ----------
__global__ void xn_rows_k(const float* __restrict__ x, float* __restrict__ out) {
  int r = blockIdx.x, t = threadIdx.x;
  float v = x[(size_t)r * DXF + t];
  float s = fabsf(v);
#pragma unroll
  for (int o = 32; o > 0; o >>= 1) s += __shfl_xor(s, o);
  __shared__ float red[4];
  if ((t & 63) == 0) red[t >> 6] = s;
  __syncthreads();
  float S = (red[0] + red[1]) + (red[2] + red[3]);
  float inv = 1.f / fmaxf(S, 1e-12f);
  out[(size_t)r * DXF + t] = v * inv;
}

// ---------- generic NT gemm: C[M,Nc] = A[M,K] @ W[Nc,K]^T + bias ----------
// EPI==1: C = elu(C)+res
template <int EPI>
__global__ __launch_bounds__(256) void gemm_nt_k(
    const float* __restrict__ A, int lda, const float* __restrict__ W, int ldw,
    const float* __restrict__ bias, const float* __restrict__ res,
    float* __restrict__ C, int ldc, int K) {
  __shared__ float smA[16][68];
  __shared__ float smB[16][68];
  int t = threadIdx.x;
  int bi = blockIdx.x * 64, bo = blockIdx.y * 64;
  int lrow = t >> 2, lk4 = (t & 3) * 4;
  int tx = t & 15, ty = t >> 4;
  float acc[4][4] = {};
  for (int k0 = 0; k0 < K; k0 += 16) {
    float4 a4 = *(const float4*)(A + (size_t)(bi + lrow) * lda + k0 + lk4);
    float4 b4 = *(const float4*)(W + (size_t)(bo + lrow) * ldw + k0 + lk4);
    __syncthreads();
    smA[lk4 + 0][lrow] = a4.x; smA[lk4 + 1][lrow] = a4.y;
    smA[lk4 + 2][lrow] = a4.z; smA[lk4 + 3][lrow] = a4.w;
    smB[lk4 + 0][lrow] = b4.x; smB[lk4 + 1][lrow] = b4.y;
    smB[lk4 + 2][lrow] = b4.z; smB[lk4 + 3][lrow] = b4.w;
    __syncthreads();
#pragma unroll
    for (int kk = 0; kk < 16; ++kk) {
      float4 av = *(const float4*)&smA[kk][ty * 4];
      float4 bv = *(const float4*)&smB[kk][tx * 4];
      float a_[4] = {av.x, av.y, av.z, av.w};
      float b_[4] = {bv.x, bv.y, bv.z, bv.w};
#pragma unroll
      for (int i = 0; i < 4; ++i)
#pragma unroll
        for (int o = 0; o < 4; ++o) acc[i][o] += a_[i] * b_[o];
    }
  }
#pragma unroll
  for (int i = 0; i < 4; ++i) {
    int row = bi + ty * 4 + i;
#pragma unroll
    for (int o = 0; o < 4; ++o) {
      int col = bo + tx * 4 + o;
      float cv = acc[i][o] + bias[col];
      if (EPI == 1) {
        cv = (cv > 0.f) ? cv : (expf(cv) - 1.f);
        cv += res[(size_t)row * FD + col];
      }
      C[(size_t)row * ldc + col] = cv;
    }
  }
}

// ---------- pad Wfc [512][516] -> [512][528] with zeros ----------
__global__ void wfc_pad_k(const float* __restrict__ Wfc, float* __restrict__ Wp) {
  int idx = blockIdx.x * 256 + threadIdx.x;
  if (idx >= 512 * 528) return;
  int r = idx / 528, c = idx - r * 528;
  Wp[idx] = (c < 516) ? Wfc[r * 516 + c] : 0.f;
}

// ---------- fused pairwise kernel ----------
__global__ __launch_bounds__(256, 2) void fused_attn_k(
    const float* __restrict__ kk_, const float* __restrict__ qq_,
    const float* __restrict__ vv_, const float* __restrict__ xn_,
    const float* __restrict__ Wm1, const float* __restrict__ bm1,
    const float* __restrict__ Wm2, const float* __restrict__ bm2,
    float* __restrict__ hm_part, float* __restrict__ xm_part,
    float* __restrict__ stats_part) {
  __shared__ float kT[BI][516];
  __shared__ float xnT[BI][260];
  __shared__ float smS[BJ][BI][8];
  __shared__ float axnS[BJ][BI];
  __shared__ float mixW[89];
  __shared__ float statS[BI][BJ][4];

  int t = threadIdx.x;
  int ib = blockIdx.x, chunk = blockIdx.y;
  int i0 = ib * BI;
  int j0base = chunk * CHK;

#pragma unroll
  for (int l = 0; l < 8; ++l) {
    int idx = l * 256 + t;
    int row = idx >> 7, c4 = (idx & 127) << 2;
    float4 val = *(const float4*)(kk_ + (size_t)(i0 + row) * FD + c4);
    *(float4*)&kT[row][c4] = val;
  }
#pragma unroll
  for (int l = 0; l < 4; ++l) {
    int idx = l * 256 + t;
    int row = idx >> 6, c4 = (idx & 63) << 2;
    float4 val = *(const float4*)(xn_ + (size_t)(i0 + row) * DXF + c4);
    *(float4*)&xnT[row][c4] = val;
  }
  if (t < 72) mixW[t] = Wm1[t];
  else if (t < 80) mixW[t] = bm1[t - 72];
  else if (t < 88) mixW[t] = Wm2[t - 80];
  else if (t == 88) mixW[88] = bm2[0];
  __syncthreads();

  int ti = t >> 4, tc = t & 15;  // tc doubles as tj in phase 1
  int ig = i0 + ti;

  float hm_frag[32];
  float xm_frag[16];
#pragma unroll
  for (int c = 0; c < 32; ++c) hm_frag[c] = 0.f;
#pragma unroll
  for (int c = 0; c < 16; ++c) xm_frag[c] = 0.f;
  float acc_abs = 0.f, acc_sum = 0.f, acc_sq = 0.f, acc_max = -1e30f;

  for (int tile = 0; tile < TILES; ++tile) {
    int j0 = j0base + tile * BJ;
    // ---- phase 1: scores + mixing + softmax + stats ----
    {
      int j = j0 + tc;
      const float4* qrow = (const float4*)(qq_ + (size_t)j * FD);
      float s[8];
#pragma unroll
      for (int b2 = 0; b2 < 8; ++b2) s[b2] = 0.f;
#pragma unroll 4
      for (int y = 0; y < 64; ++y) {
        float4 ka = *(const float4*)&kT[ti][y * 8];
        float4 kb = *(const float4*)&kT[ti][y * 8 + 4];
        float4 qa = qrow[y * 2];
        float4 qb = qrow[y * 2 + 1];
        s[0] += ka.x * qa.x; s[1] += ka.y * qa.y; s[2] += ka.z * qa.z; s[3] += ka.w * qa.w;
        s[4] += kb.x * qb.x; s[5] += kb.y * qb.y; s[6] += kb.z * qb.z; s[7] += kb.w * qb.w;
      }
      const float4* xrow = (const float4*)(xn_ + (size_t)j * DXF);
      float ax = 0.f;
#pragma unroll 4
      for (int d = 0; d < 64; ++d) {
        float4 xa = *(const float4*)&xnT[ti][d * 4];
        float4 xb = xrow[d];
        ax += xa.x * xb.x + xa.y * xb.y + xa.z * xb.z + xa.w * xb.w;
      }
      float m[8];
#pragma unroll
      for (int o = 0; o < 8; ++o) {
        float a = mixW[72 + o] + mixW[o * 9] * ax;
#pragma unroll
        for (int b2 = 0; b2 < 8; ++b2) a += mixW[o * 9 + 1 + b2] * s[b2];
        m[o] = a;
      }
      float axn = mixW[88] + ax;
#pragma unroll
      for (int o = 0; o < 8; ++o) axn += mixW[80 + o] * m[o];
      float mx = m[0];
#pragma unroll
      for (int o = 1; o < 8; ++o) mx = fmaxf(mx, m[o]);
      float es[8], esum = 0.f;
#pragma unroll
      for (int o = 0; o < 8; ++o) { es[o] = __expf(m[o] - mx); esum += es[o]; }
      float inv = 1.f / esum;
      acc_abs += fabsf(axn); acc_sum += axn; acc_sq += axn * axn;
      acc_max = fmaxf(acc_max, axn);
      if (j == ig) stats_part[((size_t)chunk * NN + ig) * 8 + 4] = axn;
      float4 sm0 = make_float4(es[0] * inv, es[1] * inv, es[2] * inv, es[3] * inv);
      float4 sm1 = make_float4(es[4] * inv, es[5] * inv, es[6] * inv, es[7] * inv);
      *(float4*)&smS[tc][ti][0] = sm0;
      *(float4*)&smS[tc][ti][4] = sm1;
      axnS[tc][ti] = axn;
    }
    __syncthreads();
    // ---- phase 2: accumulate hm, xm ----
    {
#pragma unroll 2
      for (int jj = 0; jj < BJ; ++jj) {
        int j = j0 + jj;
        float4 sa = *(const float4*)&smS[jj][ti][0];
        float4 sb = *(const float4*)&smS[jj][ti][4];
        float s8[8] = {sa.x, sa.y, sa.z, sa.w, sb.x, sb.y, sb.z, sb.w};
        float axv = axnS[jj][ti];
        const float4* vrow = (const float4*)(vv_ + (size_t)j * FD + tc * 32);
#pragma unroll
        for (int c4 = 0; c4 < 8; ++c4) {
          float4 vv = vrow[c4];
          int cb = c4 * 4;
          hm_frag[cb + 0] += s8[(cb + 0) & 7] * vv.x;
          hm_frag[cb + 1] += s8[(cb + 1) & 7] * vv.y;
          hm_frag[cb + 2] += s8[(cb + 2) & 7] * vv.z;
          hm_frag[cb + 3] += s8[(cb + 3) & 7] * vv.w;
        }
        const float4* xrow2 = (const float4*)(xn_ + (size_t)j * DXF + tc * 16);
#pragma unroll
        for (int c4 = 0; c4 < 4; ++c4) {
          float4 xv = xrow2[c4];
          int cb = c4 * 4;
          xm_frag[cb + 0] += axv * xv.x; xm_frag[cb + 1] += axv * xv.y;
          xm_frag[cb + 2] += axv * xv.z; xm_frag[cb + 3] += axv * xv.w;
        }
      }
    }
    __syncthreads();
  }
  // write partials
  {
    float* hp = hm_part + ((size_t)chunk * NN + ig) * FD + tc * 32;
#pragma unroll
    for (int c4 = 0; c4 < 8; ++c4)
      *(float4*)(hp + c4 * 4) = make_float4(hm_frag[c4 * 4], hm_frag[c4 * 4 + 1],
                                            hm_frag[c4 * 4 + 2], hm_frag[c4 * 4 + 3]);
    float* xp = xm_part + ((size_t)chunk * NN + ig) * DXF + tc * 16;
#pragma unroll
    for (int c4 = 0; c4 < 4; ++c4)
      *(float4*)(xp + c4 * 4) = make_float4(xm_frag[c4 * 4], xm_frag[c4 * 4 + 1],
                                            xm_frag[c4 * 4 + 2], xm_frag[c4 * 4 + 3]);
  }
  statS[ti][tc][0] = acc_abs;
  statS[ti][tc][1] = acc_sum;
  statS[ti][tc][2] = acc_sq;
  statS[ti][tc][3] = acc_max;
  __syncthreads();
  if (tc == 0) {
    float sab = 0.f, ss = 0.f, sq = 0.f, mxv = -1e30f;
#pragma unroll
    for (int u = 0; u < BJ; ++u) {
      sab += statS[ti][u][0]; ss += statS[ti][u][1];
      sq += statS[ti][u][2]; mxv = fmaxf(mxv, statS[ti][u][3]);
    }
    size_t base = ((size_t)chunk * NN + ig) * 8;
    stats_part[base + 0] = sab; stats_part[base + 1] = ss;
    stats_part[base + 2] = sq;  stats_part[base + 3] = mxv;
  }
}

// ---------- epilogue 1: combine partials, residuals, LN, stats, xm out ----------
__global__ void epilogue1_k(
    const float* __restrict__ h, const float* __restrict__ x,
    const float* __restrict__ hm_part, const float* __restrict__ xm_part,
    const float* __restrict__ stats_part,
    const float* __restrict__ lnf_g, const float* __restrict__ lnf_b,
    float* __restrict__ hm_full, float* __restrict__ hf_ext,
    float* __restrict__ out_xm) {
  int r = blockIdx.x, t = threadIdx.x;
  float2 acc = ((const float2*)(h + (size_t)r * FD))[t];
#pragma unroll
  for (int ch = 0; ch < JC; ++ch) {
    float2 p = ((const float2*)(hm_part + ((size_t)ch * NN + r) * FD))[t];
    acc.x += p.x; acc.y += p.y;
  }
  ((float2*)(hm_full + (size_t)r * FD))[t] = acc;
  float2 w = make_float2(acc.x + acc.y, acc.x * acc.x + acc.y * acc.y);
#pragma unroll
  for (int o = 32; o > 0; o >>= 1) { w.x += __shfl_xor(w.x, o); w.y += __shfl_xor(w.y, o); }
  __shared__ float red[4][2];
  __shared__ float s_inv;
  if ((t & 63) == 0) { red[t >> 6][0] = w.x; red[t >> 6][1] = w.y; }
  __syncthreads();
  float S  = (red[0][0] + red[1][0]) + (red[2][0] + red[3][0]);
  float SQ = (red[0][1] + red[1][1]) + (red[2][1] + red[3][1]);
  float mean = S * (1.f / FD);
  float var  = SQ * (1.f / FD) - mean * mean;
  float rs = rsqrtf(var + 1e-5f);
  float2 g2 = ((const float2*)lnf_g)[t], b2 = ((const float2*)lnf_b)[t];
  float2 o2;
  o2.x = (acc.x - mean) * rs * g2.x + b2.x;
  o2.y = (acc.y - mean) * rs * g2.y + b2.y;
  ((float2*)(hf_ext + (size_t)r * 528))[t] = o2;
  if (t == 0) {
    float sab = 0.f, ss = 0.f, sq = 0.f, mx = -1e30f;
    for (int ch = 0; ch < JC; ++ch) {
      size_t b = ((size_t)ch * NN + r) * 8;
      sab += stats_part[b + 0]; ss += stats_part[b + 1];
      sq += stats_part[b + 2];  mx = fmaxf(mx, stats_part[b + 3]);
    }
    float diag = stats_part[((size_t)(r >> 9) * NN + r) * 8 + 4];
    float L1 = fmaxf(sab, 1e-12f);
    float inv = 1.f / L1;
    float stdv = sqrtf(fmaxf((sq - ss * ss * (1.f / 2048.f)) * (1.f / 2047.f), 0.f)) * inv;
    float* he = hf_ext + (size_t)r * 528;
    he[512] = diag * inv; he[513] = ss * inv; he[514] = stdv; he[515] = mx * inv;
    s_inv = inv;
  }
  if (t < 12) hf_ext[(size_t)r * 528 + 516 + t] = 0.f;
  __syncthreads();
  float inv = s_inv;
  float xv = 0.f;
#pragma unroll
  for (int ch = 0; ch < JC; ++ch) xv += xm_part[((size_t)ch * NN + r) * DXF + t];
  out_xm[(size_t)r * DXF + t] = xv * inv + x[(size_t)r * DXF + t];
}

extern "C" void kernel_launch(void* const* d_in, const int* in_sizes, int n_in,
                              void* d_out, int out_size, void* d_ws, size_t ws_size,
                              hipStream_t stream) {
  (void)in_sizes; (void)n_in; (void)out_size; (void)ws_size;
  const float* h    = (const float*)d_in[0];
  const float* x    = (const float*)d_in[1];
  const float* ln_g = (const float*)d_in[2];
  const float* ln_b = (const float*)d_in[3];
  const float* Wk   = (const float*)d_in[4];
  const float* bk   = (const float*)d_in[5];
  const float* Wq   = (const float*)d_in[6];
  const float* bq   = (const float*)d_in[7];
  const float* Wv   = (const float*)d_in[8];
  const float* bv   = (const float*)d_in[9];
  const float* Wm1  = (const float*)d_in[10];
  const float* bm1  = (const float*)d_in[11];
  const float* Wm2  = (const float*)d_in[12];
  const float* bm2  = (const float*)d_in[13];
  const float* lnf_g = (const float*)d_in[14];
  const float* lnf_b = (const float*)d_in[15];
  const float* Wfc  = (const float*)d_in[16];
  const float* bfc  = (const float*)d_in[17];

  float* ws  = (float*)d_ws;
  float* hn  = ws;
  float* xn  = hn + (size_t)NN * FD;
  float* kb  = xn + (size_t)NN * DXF;
  float* qb  = kb + (size_t)NN * FD;
  float* vb  = qb + (size_t)NN * FD;
  float* hmp = vb + (size_t)NN * FD;
  float* xmp = hmp + (size_t)JC * NN * FD;
  float* stp = xmp + (size_t)JC * NN * DXF;
  float* hmf = stp + (size_t)JC * NN * 8;
  float* hfe = hmf + (size_t)NN * FD;
  float* wfp = hfe + (size_t)NN * 528;
  float* out_hf = (float*)d_out;
  float* out_xm = out_hf + (size_t)NN * FD;

  ln_rows_k<<<NN, 256, 0, stream>>>(h, ln_g, ln_b, hn);
  xn_rows_k<<<NN, 256, 0, stream>>>(x, xn);
  dim3 gg(32, 8);
  gemm_nt_k<0><<<gg, 256, 0, stream>>>(hn, FD, Wk, FD, bk, nullptr, kb, FD, FD);
  gemm_nt_k<0><<<gg, 256, 0, stream>>>(hn, FD, Wq, FD, bq, nullptr, qb, FD, FD);
  gemm_nt_k<0><<<gg, 256, 0, stream>>>(hn, FD, Wv, FD, bv, nullptr, vb, FD, FD);
  wfc_pad_k<<<(512 * 528 + 255) / 256, 256, 0, stream>>>(Wfc, wfp);
  dim3 gf(NN / BI, JC);
  fused_attn_k<<<gf, 256, 0, stream>>>(kb, qb, vb, xn, Wm1, bm1, Wm2, bm2, hmp, xmp, stp);
  epilogue1_k<<<NN, 256, 0, stream>>>(h, x, hmp, xmp, stp, lnf_g, lnf_b, hmf, hfe, out_xm);
  gemm_nt_k<1><<<gg, 256, 0, stream>>>(hfe, 528, wfp, 528, bfc, hmf, out_hf, FD, 528);
}

// Round 2
// 685.723 us; speedup vs baseline: 3.7669x; 3.7669x over previous
//
#include <hip/hip_runtime.h>
#include <math.h>

#define NN 2048
#define FD 512
#define DXF 256
#define BI 16
#define BJ 16
#define JC 4
#define CHK 512
#define TILES (CHK/BJ)

typedef unsigned short u16;

// ---------- layernorm rows of h ----------
__global__ void ln_rows_k(const float* __restrict__ h, const float* __restrict__ g,
                          const float* __restrict__ b, float* __restrict__ out) {
  int r = blockIdx.x, t = threadIdx.x;
  float2 v = ((const float2*)(h + (size_t)r * FD))[t];
  float2 w = make_float2(v.x + v.y, v.x * v.x + v.y * v.y);
#pragma unroll
  for (int o = 32; o > 0; o >>= 1) { w.x += __shfl_xor(w.x, o); w.y += __shfl_xor(w.y, o); }
  __shared__ float red[4][2];
  if ((t & 63) == 0) { red[t >> 6][0] = w.x; red[t >> 6][1] = w.y; }
  __syncthreads();
  float S  = (red[0][0] + red[1][0]) + (red[2][0] + red[3][0]);
  float SQ = (red[0][1] + red[1][1]) + (red[2][1] + red[3][1]);
  float mean = S * (1.f / FD);
  float var  = SQ * (1.f / FD) - mean * mean;
  float rs = rsqrtf(var + 1e-5f);
  float2 gg = ((const float2*)g)[t], bb = ((const float2*)b)[t];
  float2 o2;
  o2.x = (v.x - mean) * rs * gg.x + bb.x;
  o2.y = (v.y - mean) * rs * gg.y + bb.y;
  ((float2*)(out + (size_t)r * FD))[t] = o2;
}

// ---------- l1 normalize rows of x ----------
__global__ void xn_rows_k(const float* __restrict__ x, float* __restrict__ out) {
  int r = blockIdx.x, t = threadIdx.x;
  float v = x[(size_t)r * DXF + t];
  float s = fabsf(v);
#pragma unroll
  for (int o = 32; o > 0; o >>= 1) s += __shfl_xor(s, o);
  __shared__ float red[4];
  if ((t & 63) == 0) red[t >> 6] = s;
  __syncthreads();
  float S = (red[0] + red[1]) + (red[2] + red[3]);
  float inv = 1.f / fmaxf(S, 1e-12f);
  out[(size_t)r * DXF + t] = v * inv;
}

// ---------- generic NT gemm: C[M,Nc] = A[M,K] @ W[Nc,K]^T + bias ----------
template <int EPI>
__global__ __launch_bounds__(256) void gemm_nt_k(
    const float* __restrict__ A, int lda, const float* __restrict__ W, int ldw,
    const float* __restrict__ bias, const float* __restrict__ res,
    float* __restrict__ C, int ldc, int K) {
  __shared__ float smA[16][68];
  __shared__ float smB[16][68];
  int t = threadIdx.x;
  int bi = blockIdx.x * 64, bo = blockIdx.y * 64;
  int lrow = t >> 2, lk4 = (t & 3) * 4;
  int tx = t & 15, ty = t >> 4;
  float acc[4][4] = {};
  for (int k0 = 0; k0 < K; k0 += 16) {
    float4 a4 = *(const float4*)(A + (size_t)(bi + lrow) * lda + k0 + lk4);
    float4 b4 = *(const float4*)(W + (size_t)(bo + lrow) * ldw + k0 + lk4);
    __syncthreads();
    smA[lk4 + 0][lrow] = a4.x; smA[lk4 + 1][lrow] = a4.y;
    smA[lk4 + 2][lrow] = a4.z; smA[lk4 + 3][lrow] = a4.w;
    smB[lk4 + 0][lrow] = b4.x; smB[lk4 + 1][lrow] = b4.y;
    smB[lk4 + 2][lrow] = b4.z; smB[lk4 + 3][lrow] = b4.w;
    __syncthreads();
#pragma unroll
    for (int kk = 0; kk < 16; ++kk) {
      float4 av = *(const float4*)&smA[kk][ty * 4];
      float4 bv = *(const float4*)&smB[kk][tx * 4];
      float a_[4] = {av.x, av.y, av.z, av.w};
      float b_[4] = {bv.x, bv.y, bv.z, bv.w};
#pragma unroll
      for (int i = 0; i < 4; ++i)
#pragma unroll
        for (int o = 0; o < 4; ++o) acc[i][o] += a_[i] * b_[o];
    }
  }
#pragma unroll
  for (int i = 0; i < 4; ++i) {
    int row = bi + ty * 4 + i;
#pragma unroll
    for (int o = 0; o < 4; ++o) {
      int col = bo + tx * 4 + o;
      float cv = acc[i][o] + bias[col];
      if (EPI == 1) {
        cv = (cv > 0.f) ? cv : (expf(cv) - 1.f);
        cv += res[(size_t)row * FD + col];
      }
      C[(size_t)row * ldc + col] = cv;
    }
  }
}

// ---------- pad Wfc [512][516] -> [512][528] with zeros ----------
__global__ void wfc_pad_k(const float* __restrict__ Wfc, float* __restrict__ Wp) {
  int idx = blockIdx.x * 256 + threadIdx.x;
  if (idx >= 512 * 528) return;
  int r = idx / 528, c = idx - r * 528;
  Wp[idx] = (c < 516) ? Wfc[r * 516 + c] : 0.f;
}

// ---------- bf16 helpers ----------
__device__ __forceinline__ float blo(unsigned u) { return __uint_as_float(u << 16); }
__device__ __forceinline__ float bhi(unsigned u) { return __uint_as_float(u & 0xffff0000u); }
__device__ __forceinline__ unsigned pkbf(float a, float b) {
  unsigned ua = __float_as_uint(a), ub = __float_as_uint(b);
  ua += 0x7fffu + ((ua >> 16) & 1u);
  ub += 0x7fffu + ((ub >> 16) & 1u);
  return (ua >> 16) | (ub & 0xffff0000u);
}
// copy 32 floats (cols seg*32..) of a 512-col row into bf16 LDS row
__device__ __forceinline__ void stage512(const float* __restrict__ s, u16* d, int seg) {
  const float4* s4 = (const float4*)(s + seg * 32);
  u16* dd = d + seg * 32;
#pragma unroll
  for (int k2 = 0; k2 < 4; ++k2) {
    float4 a = s4[2 * k2], b = s4[2 * k2 + 1];
    uint4 u = make_uint4(pkbf(a.x, a.y), pkbf(a.z, a.w), pkbf(b.x, b.y), pkbf(b.z, b.w));
    *(uint4*)(dd + k2 * 8) = u;
  }
}
// copy 16 floats (cols seg*16..) of a 256-col row into bf16 LDS row
__device__ __forceinline__ void stage256(const float* __restrict__ s, u16* d, int seg) {
  const float4* s4 = (const float4*)(s + seg * 16);
  u16* dd = d + seg * 16;
#pragma unroll
  for (int k2 = 0; k2 < 2; ++k2) {
    float4 a = s4[2 * k2], b = s4[2 * k2 + 1];
    uint4 u = make_uint4(pkbf(a.x, a.y), pkbf(a.z, a.w), pkbf(b.x, b.y), pkbf(b.z, b.w));
    *(uint4*)(dd + k2 * 8) = u;
  }
}

// ---------- fused pairwise kernel (bf16 LDS staging) ----------
// LDS arena layout (bytes):
//   kT   @ 0      : 16 rows x 520 u16 = 16640
//   xnT  @ 16640  : 16 rows x 264 u16 =  8448
//   qT   @ 25088  : 16 rows x 520 u16 = 16640   (aliased by statS at end)
//   vT   @ 41728  : 16 rows x 520 u16 = 16640
//   xnJ  @ 58368  : 16 rows x 264 u16 =  8448
//   smS  @ 66816  : [16][16][8] f32   =  8192
//   axnS @ 75008  : [16][16] f32      =  1024
//   total 76032 -> 2 blocks/CU (152064 <= 163840)
__global__ __launch_bounds__(256, 2) void fused_attn_k(
    const float* __restrict__ kk_, const float* __restrict__ qq_,
    const float* __restrict__ vv_, const float* __restrict__ xn_,
    const float* __restrict__ Wm1, const float* __restrict__ bm1,
    const float* __restrict__ Wm2, const float* __restrict__ bm2,
    float* __restrict__ hm_part, float* __restrict__ xm_part,
    float* __restrict__ stats_part) {
  __shared__ __align__(16) unsigned char arena[76032];
  u16*   kT   = (u16*)(arena);
  u16*   xnT  = (u16*)(arena + 16640);
  u16*   qT   = (u16*)(arena + 25088);
  u16*   vT   = (u16*)(arena + 41728);
  u16*   xnJ  = (u16*)(arena + 58368);
  float* smS  = (float*)(arena + 66816);
  float* axnS = (float*)(arena + 75008);
  float* statS = (float*)(arena + 25088);  // alias qT (safe: used after loop only)

  int t = threadIdx.x;
  int ib = blockIdx.x, chunk = blockIdx.y;
  int i0 = ib * BI;
  int j0base = chunk * CHK;

  // mixing weights -> registers (loop-invariant, uniform)
  float W1[8][9], B1v[8], w2[8];
#pragma unroll
  for (int o = 0; o < 8; ++o) {
    B1v[o] = bm1[o];
    w2[o] = Wm2[o];
#pragma unroll
    for (int b3 = 0; b3 < 9; ++b3) W1[o][b3] = Wm1[o * 9 + b3];
  }
  float b2v = bm2[0];

  // persistent i-side staging
  {
    int row = t >> 4, seg = t & 15;
    stage512(kk_ + (size_t)(i0 + row) * FD, kT + row * 520, seg);
    stage256(xn_ + (size_t)(i0 + row) * DXF, xnT + row * 264, seg);
  }

  int ti = t >> 4, tc = t & 15;
  int ig = i0 + ti;

  float hm_frag[32];
  float xm_frag[16];
#pragma unroll
  for (int c = 0; c < 32; ++c) hm_frag[c] = 0.f;
#pragma unroll
  for (int c = 0; c < 16; ++c) xm_frag[c] = 0.f;
  float acc_abs = 0.f, acc_sum = 0.f, acc_sq = 0.f, acc_max = -1e30f;

  for (int tile = 0; tile < TILES; ++tile) {
    int j0 = j0base + tile * BJ;
    __syncthreads();  // prev phase-2 readers done (and covers persistent staging at tile 0)
    {
      int row = t >> 4, seg = t & 15;
      stage512(qq_ + (size_t)(j0 + row) * FD, qT + row * 520, seg);
      stage512(vv_ + (size_t)(j0 + row) * FD, vT + row * 520, seg);
      stage256(xn_ + (size_t)(j0 + row) * DXF, xnJ + row * 264, seg);
    }
    __syncthreads();
    // ---- phase 1: scores + mixing + softmax + stats ----
    {
      int j = j0 + tc;
      const u16* kr = kT + ti * 520;
      const u16* qr = qT + tc * 520;
      float s[8] = {0.f, 0.f, 0.f, 0.f, 0.f, 0.f, 0.f, 0.f};
#pragma unroll 8
      for (int y = 0; y < 64; ++y) {
        uint4 ku = *(const uint4*)(kr + y * 8);
        uint4 qu = *(const uint4*)(qr + y * 8);
        s[0] += blo(ku.x) * blo(qu.x);
        s[1] += bhi(ku.x) * bhi(qu.x);
        s[2] += blo(ku.y) * blo(qu.y);
        s[3] += bhi(ku.y) * bhi(qu.y);
        s[4] += blo(ku.z) * blo(qu.z);
        s[5] += bhi(ku.z) * bhi(qu.z);
        s[6] += blo(ku.w) * blo(qu.w);
        s[7] += bhi(ku.w) * bhi(qu.w);
      }
      const u16* xi = xnT + ti * 264;
      const u16* xj = xnJ + tc * 264;
      float ax = 0.f;
#pragma unroll 4
      for (int d = 0; d < 32; ++d) {
        uint4 a = *(const uint4*)(xi + d * 8);
        uint4 b = *(const uint4*)(xj + d * 8);
        ax += blo(a.x) * blo(b.x) + bhi(a.x) * bhi(b.x)
            + blo(a.y) * blo(b.y) + bhi(a.y) * bhi(b.y)
            + blo(a.z) * blo(b.z) + bhi(a.z) * bhi(b.z)
            + blo(a.w) * blo(b.w) + bhi(a.w) * bhi(b.w);
      }
      float m[8];
#pragma unroll
      for (int o = 0; o < 8; ++o) {
        float a = B1v[o] + W1[o][0] * ax;
#pragma unroll
        for (int b2 = 0; b2 < 8; ++b2) a += W1[o][1 + b2] * s[b2];
        m[o] = a;
      }
      float axn = b2v + ax;
#pragma unroll
      for (int o = 0; o < 8; ++o) axn += w2[o] * m[o];
      float mx = m[0];
#pragma unroll
      for (int o = 1; o < 8; ++o) mx = fmaxf(mx, m[o]);
      float es[8], esum = 0.f;
#pragma unroll
      for (int o = 0; o < 8; ++o) { es[o] = __expf(m[o] - mx); esum += es[o]; }
      float inv = 1.f / esum;
      acc_abs += fabsf(axn); acc_sum += axn; acc_sq += axn * axn;
      acc_max = fmaxf(acc_max, axn);
      if (j == ig) stats_part[((size_t)chunk * NN + ig) * 8 + 4] = axn;
      float* sp = smS + (tc * 16 + ti) * 8;
      *(float4*)(sp)     = make_float4(es[0] * inv, es[1] * inv, es[2] * inv, es[3] * inv);
      *(float4*)(sp + 4) = make_float4(es[4] * inv, es[5] * inv, es[6] * inv, es[7] * inv);
      axnS[tc * 16 + ti] = axn;
    }
    __syncthreads();
    // ---- phase 2: accumulate hm (cols ch*64 + tc*4), xm ----
    {
      const float4* smp = (const float4*)smS;
#pragma unroll 2
      for (int jj = 0; jj < BJ; ++jj) {
        float4 sv = smp[(jj * 16 + ti) * 2 + (tc & 1)];  // heads 0-3 (even tc) / 4-7 (odd tc)
        float axv = axnS[jj * 16 + ti];
        const u16* vr = vT + jj * 520 + tc * 4;
#pragma unroll
        for (int ch = 0; ch < 8; ++ch) {
          uint2 vu = *(const uint2*)(vr + ch * 64);
          hm_frag[ch * 4 + 0] += sv.x * blo(vu.x);
          hm_frag[ch * 4 + 1] += sv.y * bhi(vu.x);
          hm_frag[ch * 4 + 2] += sv.z * blo(vu.y);
          hm_frag[ch * 4 + 3] += sv.w * bhi(vu.y);
        }
        const u16* xr = xnJ + jj * 264 + tc * 4;
#pragma unroll
        for (int ch = 0; ch < 4; ++ch) {
          uint2 xu = *(const uint2*)(xr + ch * 64);
          xm_frag[ch * 4 + 0] += axv * blo(xu.x);
          xm_frag[ch * 4 + 1] += axv * bhi(xu.x);
          xm_frag[ch * 4 + 2] += axv * blo(xu.y);
          xm_frag[ch * 4 + 3] += axv * bhi(xu.y);
        }
      }
    }
  }
  // write partials (col = ch*64 + tc*4 + e)
  {
    float* hp = hm_part + ((size_t)chunk * NN + ig) * FD + tc * 4;
#pragma unroll
    for (int ch = 0; ch < 8; ++ch)
      *(float4*)(hp + ch * 64) = make_float4(hm_frag[ch * 4], hm_frag[ch * 4 + 1],
                                             hm_frag[ch * 4 + 2], hm_frag[ch * 4 + 3]);
    float* xp = xm_part + ((size_t)chunk * NN + ig) * DXF + tc * 4;
#pragma unroll
    for (int ch = 0; ch < 4; ++ch)
      *(float4*)(xp + ch * 64) = make_float4(xm_frag[ch * 4], xm_frag[ch * 4 + 1],
                                             xm_frag[ch * 4 + 2], xm_frag[ch * 4 + 3]);
  }
  statS[(ti * 16 + tc) * 4 + 0] = acc_abs;
  statS[(ti * 16 + tc) * 4 + 1] = acc_sum;
  statS[(ti * 16 + tc) * 4 + 2] = acc_sq;
  statS[(ti * 16 + tc) * 4 + 3] = acc_max;
  __syncthreads();
  if (tc == 0) {
    float sab = 0.f, ss = 0.f, sq = 0.f, mxv = -1e30f;
#pragma unroll
    for (int u = 0; u < BJ; ++u) {
      sab += statS[(ti * 16 + u) * 4 + 0];
      ss  += statS[(ti * 16 + u) * 4 + 1];
      sq  += statS[(ti * 16 + u) * 4 + 2];
      mxv = fmaxf(mxv, statS[(ti * 16 + u) * 4 + 3]);
    }
    size_t base = ((size_t)chunk * NN + ig) * 8;
    stats_part[base + 0] = sab; stats_part[base + 1] = ss;
    stats_part[base + 2] = sq;  stats_part[base + 3] = mxv;
  }
}

// ---------- epilogue 1: combine partials, residuals, LN, stats, xm out ----------
__global__ void epilogue1_k(
    const float* __restrict__ h, const float* __restrict__ x,
    const float* __restrict__ hm_part, const float* __restrict__ xm_part,
    const float* __restrict__ stats_part,
    const float* __restrict__ lnf_g, const float* __restrict__ lnf_b,
    float* __restrict__ hm_full, float* __restrict__ hf_ext,
    float* __restrict__ out_xm) {
  int r = blockIdx.x, t = threadIdx.x;
  float2 acc = ((const float2*)(h + (size_t)r * FD))[t];
#pragma unroll
  for (int ch = 0; ch < JC; ++ch) {
    float2 p = ((const float2*)(hm_part + ((size_t)ch * NN + r) * FD))[t];
    acc.x += p.x; acc.y += p.y;
  }
  ((float2*)(hm_full + (size_t)r * FD))[t] = acc;
  float2 w = make_float2(acc.x + acc.y, acc.x * acc.x + acc.y * acc.y);
#pragma unroll
  for (int o = 32; o > 0; o >>= 1) { w.x += __shfl_xor(w.x, o); w.y += __shfl_xor(w.y, o); }
  __shared__ float red[4][2];
  __shared__ float s_inv;
  if ((t & 63) == 0) { red[t >> 6][0] = w.x; red[t >> 6][1] = w.y; }
  __syncthreads();
  float S  = (red[0][0] + red[1][0]) + (red[2][0] + red[3][0]);
  float SQ = (red[0][1] + red[1][1]) + (red[2][1] + red[3][1]);
  float mean = S * (1.f / FD);
  float var  = SQ * (1.f / FD) - mean * mean;
  float rs = rsqrtf(var + 1e-5f);
  float2 g2 = ((const float2*)lnf_g)[t], b2 = ((const float2*)lnf_b)[t];
  float2 o2;
  o2.x = (acc.x - mean) * rs * g2.x + b2.x;
  o2.y = (acc.y - mean) * rs * g2.y + b2.y;
  ((float2*)(hf_ext + (size_t)r * 528))[t] = o2;
  if (t == 0) {
    float sab = 0.f, ss = 0.f, sq = 0.f, mx = -1e30f;
    for (int ch = 0; ch < JC; ++ch) {
      size_t b = ((size_t)ch * NN + r) * 8;
      sab += stats_part[b + 0]; ss += stats_part[b + 1];
      sq += stats_part[b + 2];  mx = fmaxf(mx, stats_part[b + 3]);
    }
    float diag = stats_part[((size_t)(r >> 9) * NN + r) * 8 + 4];
    float L1 = fmaxf(sab, 1e-12f);
    float inv = 1.f / L1;
    float stdv = sqrtf(fmaxf((sq - ss * ss * (1.f / 2048.f)) * (1.f / 2047.f), 0.f)) * inv;
    float* he = hf_ext + (size_t)r * 528;
    he[512] = diag * inv; he[513] = ss * inv; he[514] = stdv; he[515] = mx * inv;
    s_inv = inv;
  }
  if (t < 12) hf_ext[(size_t)r * 528 + 516 + t] = 0.f;
  __syncthreads();
  float inv = s_inv;
  float xv = 0.f;
#pragma unroll
  for (int ch = 0; ch < JC; ++ch) xv += xm_part[((size_t)ch * NN + r) * DXF + t];
  out_xm[(size_t)r * DXF + t] = xv * inv + x[(size_t)r * DXF + t];
}

extern "C" void kernel_launch(void* const* d_in, const int* in_sizes, int n_in,
                              void* d_out, int out_size, void* d_ws, size_t ws_size,
                              hipStream_t stream) {
  (void)in_sizes; (void)n_in; (void)out_size; (void)ws_size;
  const float* h    = (const float*)d_in[0];
  const float* x    = (const float*)d_in[1];
  const float* ln_g = (const float*)d_in[2];
  const float* ln_b = (const float*)d_in[3];
  const float* Wk   = (const float*)d_in[4];
  const float* bk   = (const float*)d_in[5];
  const float* Wq   = (const float*)d_in[6];
  const float* bq   = (const float*)d_in[7];
  const float* Wv   = (const float*)d_in[8];
  const float* bv   = (const float*)d_in[9];
  const float* Wm1  = (const float*)d_in[10];
  const float* bm1  = (const float*)d_in[11];
  const float* Wm2  = (const float*)d_in[12];
  const float* bm2  = (const float*)d_in[13];
  const float* lnf_g = (const float*)d_in[14];
  const float* lnf_b = (const float*)d_in[15];
  const float* Wfc  = (const float*)d_in[16];
  const float* bfc  = (const float*)d_in[17];

  float* ws  = (float*)d_ws;
  float* hn  = ws;
  float* xn  = hn + (size_t)NN * FD;
  float* kb  = xn + (size_t)NN * DXF;
  float* qb  = kb + (size_t)NN * FD;
  float* vb  = qb + (size_t)NN * FD;
  float* hmp = vb + (size_t)NN * FD;
  float* xmp = hmp + (size_t)JC * NN * FD;
  float* stp = xmp + (size_t)JC * NN * DXF;
  float* hmf = stp + (size_t)JC * NN * 8;
  float* hfe = hmf + (size_t)NN * FD;
  float* wfp = hfe + (size_t)NN * 528;
  float* out_hf = (float*)d_out;
  float* out_xm = out_hf + (size_t)NN * FD;

  ln_rows_k<<<NN, 256, 0, stream>>>(h, ln_g, ln_b, hn);
  xn_rows_k<<<NN, 256, 0, stream>>>(x, xn);
  dim3 gg(32, 8);
  gemm_nt_k<0><<<gg, 256, 0, stream>>>(hn, FD, Wk, FD, bk, nullptr, kb, FD, FD);
  gemm_nt_k<0><<<gg, 256, 0, stream>>>(hn, FD, Wq, FD, bq, nullptr, qb, FD, FD);
  gemm_nt_k<0><<<gg, 256, 0, stream>>>(hn, FD, Wv, FD, bv, nullptr, vb, FD, FD);
  wfc_pad_k<<<(512 * 528 + 255) / 256, 256, 0, stream>>>(Wfc, wfp);
  dim3 gf(NN / BI, JC);
  fused_attn_k<<<gf, 256, 0, stream>>>(kb, qb, vb, xn, Wm1, bm1, Wm2, bm2, hmp, xmp, stp);
  epilogue1_k<<<NN, 256, 0, stream>>>(h, x, hmp, xmp, stp, lnf_g, lnf_b, hmf, hfe, out_xm);
  gemm_nt_k<1><<<gg, 256, 0, stream>>>(hfe, 528, wfp, 528, bfc, hmf, out_hf, FD, 528);
}

// Round 3
// 284.707 us; speedup vs baseline: 9.0727x; 2.4085x over previous
//
#include <hip/hip_runtime.h>
#include <math.h>

#define NN 2048
#define FD 512
#define DXF 256
#define JC 4
#define CHKJ 512
#define ITI 32
#define JIT 32
#define NIT (CHKJ/JIT)

typedef unsigned short u16;
typedef unsigned int u32;
typedef __attribute__((ext_vector_type(8))) short s16x8;
typedef __attribute__((ext_vector_type(4))) float f32x4;

__device__ __forceinline__ f32x4 MFMA16(s16x8 a, s16x8 b, f32x4 c) {
  return __builtin_amdgcn_mfma_f32_16x16x32_bf16(a, b, c, 0, 0, 0);
}
__device__ __forceinline__ u16 bf1(float f) {
  u32 u = __float_as_uint(f);
  u += 0x7fffu + ((u >> 16) & 1u);
  return (u16)(u >> 16);
}
__device__ __forceinline__ unsigned pkbf(float a, float b) {
  u32 ua = __float_as_uint(a), ub = __float_as_uint(b);
  ua += 0x7fffu + ((ua >> 16) & 1u);
  ub += 0x7fffu + ((ub >> 16) & 1u);
  return (ua >> 16) | (ub & 0xffff0000u);
}
__device__ __forceinline__ s16x8 ldfrag(const unsigned char* p) {
  return *(const s16x8*)p;
}

// ---------- layernorm rows of h ----------
__global__ void ln_rows_k(const float* __restrict__ h, const float* __restrict__ g,
                          const float* __restrict__ b, float* __restrict__ out) {
  int r = blockIdx.x, t = threadIdx.x;
  float2 v = ((const float2*)(h + (size_t)r * FD))[t];
  float2 w = make_float2(v.x + v.y, v.x * v.x + v.y * v.y);
#pragma unroll
  for (int o = 32; o > 0; o >>= 1) { w.x += __shfl_xor(w.x, o); w.y += __shfl_xor(w.y, o); }
  __shared__ float red[4][2];
  if ((t & 63) == 0) { red[t >> 6][0] = w.x; red[t >> 6][1] = w.y; }
  __syncthreads();
  float S  = (red[0][0] + red[1][0]) + (red[2][0] + red[3][0]);
  float SQ = (red[0][1] + red[1][1]) + (red[2][1] + red[3][1]);
  float mean = S * (1.f / FD);
  float var  = SQ * (1.f / FD) - mean * mean;
  float rs = rsqrtf(var + 1e-5f);
  float2 gg = ((const float2*)g)[t], bb = ((const float2*)b)[t];
  float2 o2;
  o2.x = (v.x - mean) * rs * gg.x + bb.x;
  o2.y = (v.y - mean) * rs * gg.y + bb.y;
  ((float2*)(out + (size_t)r * FD))[t] = o2;
}

// ---------- l1 normalize rows of x -> bf16 ----------
__global__ void xn_rows_k(const float* __restrict__ x, u16* __restrict__ out) {
  int r = blockIdx.x, t = threadIdx.x;
  float v = x[(size_t)r * DXF + t];
  float s = fabsf(v);
#pragma unroll
  for (int o = 32; o > 0; o >>= 1) s += __shfl_xor(s, o);
  __shared__ float red[4];
  if ((t & 63) == 0) red[t >> 6] = s;
  __syncthreads();
  float S = (red[0] + red[1]) + (red[2] + red[3]);
  float inv = 1.f / fmaxf(S, 1e-12f);
  out[(size_t)r * DXF + t] = bf1(v * inv);
}

// ---------- generic NT gemm ----------
template <int EPI>
__global__ __launch_bounds__(256) void gemm_nt_k(
    const float* __restrict__ A, int lda, const float* __restrict__ W, int ldw,
    const float* __restrict__ bias, const float* __restrict__ res,
    float* __restrict__ C, int ldc, int K) {
  __shared__ float smA[16][68];
  __shared__ float smB[16][68];
  int t = threadIdx.x;
  int bi = blockIdx.x * 64, bo = blockIdx.y * 64;
  int lrow = t >> 2, lk4 = (t & 3) * 4;
  int tx = t & 15, ty = t >> 4;
  float acc[4][4] = {};
  for (int k0 = 0; k0 < K; k0 += 16) {
    float4 a4 = *(const float4*)(A + (size_t)(bi + lrow) * lda + k0 + lk4);
    float4 b4 = *(const float4*)(W + (size_t)(bo + lrow) * ldw + k0 + lk4);
    __syncthreads();
    smA[lk4 + 0][lrow] = a4.x; smA[lk4 + 1][lrow] = a4.y;
    smA[lk4 + 2][lrow] = a4.z; smA[lk4 + 3][lrow] = a4.w;
    smB[lk4 + 0][lrow] = b4.x; smB[lk4 + 1][lrow] = b4.y;
    smB[lk4 + 2][lrow] = b4.z; smB[lk4 + 3][lrow] = b4.w;
    __syncthreads();
#pragma unroll
    for (int kk = 0; kk < 16; ++kk) {
      float4 av = *(const float4*)&smA[kk][ty * 4];
      float4 bv = *(const float4*)&smB[kk][tx * 4];
      float a_[4] = {av.x, av.y, av.z, av.w};
      float b_[4] = {bv.x, bv.y, bv.z, bv.w};
#pragma unroll
      for (int i = 0; i < 4; ++i)
#pragma unroll
        for (int o = 0; o < 4; ++o) acc[i][o] += a_[i] * b_[o];
    }
  }
#pragma unroll
  for (int i = 0; i < 4; ++i) {
    int row = bi + ty * 4 + i;
#pragma unroll
    for (int o = 0; o < 4; ++o) {
      int col = bo + tx * 4 + o;
      float cv = acc[i][o] + bias[col];
      if (EPI == 1) {
        cv = (cv > 0.f) ? cv : (expf(cv) - 1.f);
        cv += res[(size_t)row * FD + col];
      }
      C[(size_t)row * ldc + col] = cv;
    }
  }
}

// ---------- pad Wfc ----------
__global__ void wfc_pad_k(const float* __restrict__ Wfc, float* __restrict__ Wp) {
  int idx = blockIdx.x * 256 + threadIdx.x;
  if (idx >= 512 * 528) return;
  int r = idx / 528, c = idx - r * 528;
  Wp[idx] = (c < 516) ? Wfc[r * 516 + c] : 0.f;
}

// ---------- repack: k,q -> planar bf16 [b][i][64]; v -> vPT [b][z][j]; xnB -> xnTg [d][j]
__global__ __launch_bounds__(256) void repack_k(
    const float* __restrict__ kb, const float* __restrict__ qb,
    const float* __restrict__ vb, const u16* __restrict__ xnB,
    u16* __restrict__ kP, u16* __restrict__ qP, u16* __restrict__ vPT,
    u16* __restrict__ xnTg) {
  __shared__ u16 tile[16][512];
  int t = threadIdx.x;
  int r0 = blockIdx.x * 16;

  // ---- phase K ----
#pragma unroll
  for (int s = 0; s < 8; ++s) {
    int c = s * 256 + t;
    int f4 = c & 127, row = c >> 7;
    float4 v = *(const float4*)(kb + (size_t)(r0 + row) * FD + f4 * 4);
    *(uint2*)&tile[row][f4 * 4] = make_uint2(pkbf(v.x, v.y), pkbf(v.z, v.w));
  }
  __syncthreads();
#pragma unroll
  for (int s = 0; s < 4; ++s) {
    int c = s * 256 + t;
    int yb = c & 7, b = (c >> 3) & 7, i = c >> 6;
    u16 e[8];
#pragma unroll
    for (int e8 = 0; e8 < 8; ++e8) e[e8] = tile[i][(yb * 8 + e8) * 8 + b];
    *(uint4*)(kP + ((size_t)(b * NN + r0 + i) * 64 + yb * 8)) = *(const uint4*)e;
  }
  __syncthreads();
  // ---- phase Q ----
#pragma unroll
  for (int s = 0; s < 8; ++s) {
    int c = s * 256 + t;
    int f4 = c & 127, row = c >> 7;
    float4 v = *(const float4*)(qb + (size_t)(r0 + row) * FD + f4 * 4);
    *(uint2*)&tile[row][f4 * 4] = make_uint2(pkbf(v.x, v.y), pkbf(v.z, v.w));
  }
  __syncthreads();
#pragma unroll
  for (int s = 0; s < 4; ++s) {
    int c = s * 256 + t;
    int yb = c & 7, b = (c >> 3) & 7, i = c >> 6;
    u16 e[8];
#pragma unroll
    for (int e8 = 0; e8 < 8; ++e8) e[e8] = tile[i][(yb * 8 + e8) * 8 + b];
    *(uint4*)(qP + ((size_t)(b * NN + r0 + i) * 64 + yb * 8)) = *(const uint4*)e;
  }
  __syncthreads();
  // ---- phase V (transposed planes) ----
#pragma unroll
  for (int s = 0; s < 8; ++s) {
    int c = s * 256 + t;
    int f4 = c & 127, row = c >> 7;
    float4 v = *(const float4*)(vb + (size_t)(r0 + row) * FD + f4 * 4);
    *(uint2*)&tile[row][f4 * 4] = make_uint2(pkbf(v.x, v.y), pkbf(v.z, v.w));
  }
  __syncthreads();
#pragma unroll
  for (int s = 0; s < 4; ++s) {
    int c = s * 256 + t;
    int jb = c & 1, z = (c >> 1) & 63, b = c >> 7;
    u16 e[8];
#pragma unroll
    for (int e8 = 0; e8 < 8; ++e8) e[e8] = tile[jb * 8 + e8][z * 8 + b];
    *(uint4*)(vPT + ((size_t)(b * 64 + z) * NN + r0 + jb * 8)) = *(const uint4*)e;
  }
  __syncthreads();
  // ---- phase xnT ----
#pragma unroll
  for (int s = 0; s < 2; ++s) {
    int c = s * 256 + t;
    int db = c & 31, row = c >> 5;
    uint4 v = *(const uint4*)(xnB + (size_t)(r0 + row) * DXF + db * 8);
    *(uint4*)&tile[row][db * 8] = v;
  }
  __syncthreads();
#pragma unroll
  for (int s = 0; s < 2; ++s) {
    int c = s * 256 + t;
    int jb = c & 1, d = c >> 1;
    u16 e[8];
#pragma unroll
    for (int e8 = 0; e8 < 8; ++e8) e[e8] = tile[jb * 8 + e8][d];
    *(uint4*)(xnTg + (size_t)d * NN + r0 + jb * 8) = *(const uint4*)e;
  }
}

// ---------- fused MFMA pairwise kernel ----------
// LDS layout (bytes):
//  kI  @0      32768  [8][32 i][128B] blk^ (i&7)
//  xnI @32768  16384  [32 i][512B]    blk^ (i&7)
//  qJ  @49152  32768  [8][32 j][128B] blk^ (j&7)   (aliased: P @49152, axn @65536, stats @67584)
//  vJ  @81920  32768  [8][64 z][64B]  blk^ ((z>>1)&3)
//  xnJ @114688 16384  [32 j][512B]    blk^ (j&7)
//  xJT @131072 16384  [256 c][64B]    blk^ ((c>>1)&3)
__global__ __launch_bounds__(256, 1) void fused_mfma_k(
    const u16* __restrict__ kP, const u16* __restrict__ qP,
    const u16* __restrict__ vPT, const u16* __restrict__ xnB,
    const u16* __restrict__ xnTg,
    const float* __restrict__ Wm1, const float* __restrict__ bm1,
    const float* __restrict__ Wm2, const float* __restrict__ bm2,
    float* __restrict__ hmP, float* __restrict__ xmP,
    float* __restrict__ stP) {
  __shared__ __align__(16) unsigned char L[147456];
  const int O_KI = 0, O_XNI = 32768, O_QJ = 49152, O_P = 49152, O_AXN = 65536,
            O_ST = 67584, O_VJ = 81920, O_XNJ = 114688, O_XJT = 131072;

  const int t = threadIdx.x;
  const int w = t >> 6, lane = t & 63;
  const int g = lane >> 4, li = lane & 15;
  const int isub = w >> 1, jsub = w & 1;
  const int i0 = blockIdx.x * ITI;
  const int chunk = blockIdx.y;

  float W1[8][9], B1v[8], w2v[8];
#pragma unroll
  for (int o = 0; o < 8; ++o) {
    B1v[o] = bm1[o];
    w2v[o] = Wm2[o];
#pragma unroll
    for (int b3 = 0; b3 < 9; ++b3) W1[o][b3] = Wm1[o * 9 + b3];
  }
  const float b2v = bm2[0];

  // i-side staging (once)
#pragma unroll
  for (int s = 0; s < 8; ++s) {
    int c = s * 256 + t;
    int yb = c & 7, il = (c >> 3) & 31, b = c >> 8;
    uint4 v = *(const uint4*)(kP + (size_t)(b * NN + i0 + il) * 64 + yb * 8);
    *(uint4*)(L + O_KI + b * 4096 + il * 128 + ((yb ^ (il & 7)) << 4)) = v;
  }
#pragma unroll
  for (int s = 0; s < 4; ++s) {
    int c = s * 256 + t;
    int db = c & 31, il = c >> 5;
    uint4 v = *(const uint4*)(xnB + (size_t)(i0 + il) * DXF + db * 8);
    *(uint4*)(L + O_XNI + il * 512 + ((db ^ (il & 7)) << 4)) = v;
  }

  f32x4 hmA[2][2][4];
  f32x4 xmA[2][4];
#pragma unroll
  for (int a = 0; a < 2; ++a)
#pragma unroll
    for (int b = 0; b < 2; ++b)
#pragma unroll
      for (int c = 0; c < 4; ++c) hmA[a][b][c] = (f32x4)(0.f);
#pragma unroll
  for (int a = 0; a < 2; ++a)
#pragma unroll
    for (int c = 0; c < 4; ++c) xmA[a][c] = (f32x4)(0.f);
  float aab[4] = {0, 0, 0, 0}, asu[4] = {0, 0, 0, 0}, asq[4] = {0, 0, 0, 0};
  float amx[4] = {-1e30f, -1e30f, -1e30f, -1e30f};

  const int iL = isub * 16 + li;
  const int jL = jsub * 16 + li;
  const int swI = iL & 7, swJ = jL & 7;

  for (int it = 0; it < NIT; ++it) {
    const int j0 = chunk * CHKJ + it * JIT;
    // stage j-side
#pragma unroll
    for (int s = 0; s < 8; ++s) {
      int c = s * 256 + t;
      int yb = c & 7, jl = (c >> 3) & 31, b = c >> 8;
      uint4 v = *(const uint4*)(qP + (size_t)(b * NN + j0 + jl) * 64 + yb * 8);
      *(uint4*)(L + O_QJ + b * 4096 + jl * 128 + ((yb ^ (jl & 7)) << 4)) = v;
    }
#pragma unroll
    for (int s = 0; s < 8; ++s) {
      int c = s * 256 + t;
      int jb = c & 3, z = (c >> 2) & 63, b = c >> 8;
      uint4 v = *(const uint4*)(vPT + (size_t)(b * 64 + z) * NN + j0 + jb * 8);
      *(uint4*)(L + O_VJ + b * 4096 + z * 64 + ((jb ^ ((z >> 1) & 3)) << 4)) = v;
    }
#pragma unroll
    for (int s = 0; s < 4; ++s) {
      int c = s * 256 + t;
      int db = c & 31, jl = c >> 5;
      uint4 v = *(const uint4*)(xnB + (size_t)(j0 + jl) * DXF + db * 8);
      *(uint4*)(L + O_XNJ + jl * 512 + ((db ^ (jl & 7)) << 4)) = v;
    }
#pragma unroll
    for (int s = 0; s < 4; ++s) {
      int c = s * 256 + t;
      int jb = c & 3, cr = c >> 2;
      uint4 v = *(const uint4*)(xnTg + (size_t)cr * NN + j0 + jb * 8);
      *(uint4*)(L + O_XJT + cr * 64 + ((jb ^ ((cr >> 1) & 3)) << 4)) = v;
    }
    __syncthreads();  // staged data visible

    // phase 1: scores
    f32x4 accS[9];
#pragma unroll
    for (int a = 0; a < 9; ++a) accS[a] = (f32x4)(0.f);
#pragma unroll
    for (int b = 0; b < 8; ++b) {
#pragma unroll
      for (int ks = 0; ks < 2; ++ks) {
        int blk = ks * 4 + g;
        s16x8 af = ldfrag(L + O_KI + b * 4096 + iL * 128 + (((blk) ^ swI) << 4));
        s16x8 bf = ldfrag(L + O_QJ + b * 4096 + jL * 128 + (((blk) ^ swJ) << 4));
        accS[b] = MFMA16(af, bf, accS[b]);
      }
    }
#pragma unroll
    for (int ks = 0; ks < 8; ++ks) {
      int blk = ks * 4 + g;
      s16x8 af = ldfrag(L + O_XNI + iL * 512 + (((blk) ^ swI) << 4));
      s16x8 bf = ldfrag(L + O_XNJ + jL * 512 + (((blk) ^ swJ) << 4));
      accS[8] = MFMA16(af, bf, accS[8]);
    }
    __syncthreads();  // all waves done reading qJ (alias target)

    // softmax + mixing + stats + P/axn writes
#pragma unroll
    for (int r = 0; r < 4; ++r) {
      float sb[8];
#pragma unroll
      for (int b = 0; b < 8; ++b) sb[b] = accS[b][r];
      float ax = accS[8][r];
      float m[8];
#pragma unroll
      for (int o = 0; o < 8; ++o) {
        float a = B1v[o] + W1[o][0] * ax;
#pragma unroll
        for (int b = 0; b < 8; ++b) a += W1[o][1 + b] * sb[b];
        m[o] = a;
      }
      float axn = b2v + ax;
#pragma unroll
      for (int o = 0; o < 8; ++o) axn += w2v[o] * m[o];
      aab[r] += fabsf(axn); asu[r] += axn; asq[r] += axn * axn;
      amx[r] = fmaxf(amx[r], axn);
      int iG = i0 + isub * 16 + g * 4 + r;
      int jG = j0 + jL;
      if (iG == jG) stP[((size_t)chunk * NN + iG) * 8 + 4] = axn;
      float mx = m[0];
#pragma unroll
      for (int o = 1; o < 8; ++o) mx = fmaxf(mx, m[o]);
      float es[8], esum = 0.f;
#pragma unroll
      for (int o = 0; o < 8; ++o) { es[o] = __expf(m[o] - mx); esum += es[o]; }
      float inv = 1.f / esum;
      int iL2 = isub * 16 + g * 4 + r;
      int base = (((jL >> 3) ^ ((iL2 >> 1) & 3)) << 4) + (jL & 7) * 2;
#pragma unroll
      for (int b = 0; b < 8; ++b)
        *(u16*)(L + O_P + b * 2048 + iL2 * 64 + base) = bf1(es[b] * inv);
      *(u16*)(L + O_AXN + iL2 * 64 + base) = bf1(axn);
    }
    __syncthreads();  // P visible

    // phase 2: PV + xm
#pragma unroll
    for (int hh = 0; hh < 2; ++hh) {
      int hd = w * 2 + hh;
      s16x8 pa[2];
#pragma unroll
      for (int is2 = 0; is2 < 2; ++is2) {
        int r2 = is2 * 16 + li;
        pa[is2] = ldfrag(L + O_P + hd * 2048 + r2 * 64 + (((g) ^ ((r2 >> 1) & 3)) << 4));
      }
#pragma unroll
      for (int zt = 0; zt < 4; ++zt) {
        int z = zt * 16 + li;
        s16x8 vf = ldfrag(L + O_VJ + hd * 4096 + z * 64 + (((g) ^ ((z >> 1) & 3)) << 4));
        hmA[hh][0][zt] = MFMA16(pa[0], vf, hmA[hh][0][zt]);
        hmA[hh][1][zt] = MFMA16(pa[1], vf, hmA[hh][1][zt]);
      }
    }
    {
      s16x8 xa[2];
#pragma unroll
      for (int is2 = 0; is2 < 2; ++is2) {
        int r2 = is2 * 16 + li;
        xa[is2] = ldfrag(L + O_AXN + r2 * 64 + (((g) ^ ((r2 >> 1) & 3)) << 4));
      }
#pragma unroll
      for (int ct = 0; ct < 4; ++ct) {
        int cc = w * 64 + ct * 16 + li;
        s16x8 xb = ldfrag(L + O_XJT + cc * 64 + (((g) ^ ((cc >> 1) & 3)) << 4));
        xmA[0][ct] = MFMA16(xa[0], xb, xmA[0][ct]);
        xmA[1][ct] = MFMA16(xa[1], xb, xmA[1][ct]);
      }
    }
    __syncthreads();  // phase-2 reads done; safe to restage
  }

  // write hm planar + xm
#pragma unroll
  for (int hh = 0; hh < 2; ++hh) {
    int hd = w * 2 + hh;
#pragma unroll
    for (int is2 = 0; is2 < 2; ++is2)
#pragma unroll
      for (int zt = 0; zt < 4; ++zt)
#pragma unroll
        for (int rg = 0; rg < 4; ++rg) {
          int iG = i0 + is2 * 16 + g * 4 + rg;
          int zG = zt * 16 + li;
          hmP[((size_t)(chunk * 8 + hd) * NN + iG) * 64 + zG] = hmA[hh][is2][zt][rg];
        }
  }
#pragma unroll
  for (int is2 = 0; is2 < 2; ++is2)
#pragma unroll
    for (int ct = 0; ct < 4; ++ct)
#pragma unroll
      for (int rg = 0; rg < 4; ++rg) {
        int iG = i0 + is2 * 16 + g * 4 + rg;
        int cc = w * 64 + ct * 16 + li;
        xmP[((size_t)chunk * NN + iG) * DXF + cc] = xmA[is2][ct][rg];
      }

  // stats: reduce over the 16 lanes sharing a row-group
#pragma unroll
  for (int off = 1; off < 16; off <<= 1) {
#pragma unroll
    for (int r = 0; r < 4; ++r) {
      aab[r] += __shfl_xor(aab[r], off);
      asu[r] += __shfl_xor(asu[r], off);
      asq[r] += __shfl_xor(asq[r], off);
      amx[r] = fmaxf(amx[r], __shfl_xor(amx[r], off));
    }
  }
  float* stl = (float*)(L + O_ST);
  if (li == 0) {
#pragma unroll
    for (int r = 0; r < 4; ++r) {
      int flat = (w * 16 + g * 4 + r) * 4;
      stl[flat + 0] = aab[r]; stl[flat + 1] = asu[r];
      stl[flat + 2] = asq[r]; stl[flat + 3] = amx[r];
    }
  }
  __syncthreads();
  if (t < 32) {
    int isb = t >> 4, rl = t & 15;
    int w0 = isb * 2;
    int f0 = (w0 * 16 + rl) * 4, f1 = ((w0 + 1) * 16 + rl) * 4;
    float sab = stl[f0 + 0] + stl[f1 + 0];
    float ssu = stl[f0 + 1] + stl[f1 + 1];
    float ssq = stl[f0 + 2] + stl[f1 + 2];
    float smx = fmaxf(stl[f0 + 3], stl[f1 + 3]);
    size_t base = ((size_t)chunk * NN + i0 + t) * 8;
    stP[base + 0] = sab; stP[base + 1] = ssu;
    stP[base + 2] = ssq; stP[base + 3] = smx;
  }
}

// ---------- epilogue 1 ----------
__global__ void epilogue1_k(
    const float* __restrict__ h, const float* __restrict__ x,
    const float* __restrict__ hm_part, const float* __restrict__ xm_part,
    const float* __restrict__ stats_part,
    const float* __restrict__ lnf_g, const float* __restrict__ lnf_b,
    float* __restrict__ hm_full, float* __restrict__ hf_ext,
    float* __restrict__ out_xm) {
  int r = blockIdx.x, t = threadIdx.x;
  int c0 = 2 * t, c1 = 2 * t + 1;
  float2 acc = ((const float2*)(h + (size_t)r * FD))[t];
#pragma unroll
  for (int ch = 0; ch < JC; ++ch) {
    acc.x += hm_part[((size_t)(ch * 8 + (c0 & 7)) * NN + r) * 64 + (c0 >> 3)];
    acc.y += hm_part[((size_t)(ch * 8 + (c1 & 7)) * NN + r) * 64 + (c1 >> 3)];
  }
  ((float2*)(hm_full + (size_t)r * FD))[t] = acc;
  float2 w = make_float2(acc.x + acc.y, acc.x * acc.x + acc.y * acc.y);
#pragma unroll
  for (int o = 32; o > 0; o >>= 1) { w.x += __shfl_xor(w.x, o); w.y += __shfl_xor(w.y, o); }
  __shared__ float red[4][2];
  __shared__ float s_inv;
  if ((t & 63) == 0) { red[t >> 6][0] = w.x; red[t >> 6][1] = w.y; }
  __syncthreads();
  float S  = (red[0][0] + red[1][0]) + (red[2][0] + red[3][0]);
  float SQ = (red[0][1] + red[1][1]) + (red[2][1] + red[3][1]);
  float mean = S * (1.f / FD);
  float var  = SQ * (1.f / FD) - mean * mean;
  float rs = rsqrtf(var + 1e-5f);
  float2 g2 = ((const float2*)lnf_g)[t], b2 = ((const float2*)lnf_b)[t];
  float2 o2;
  o2.x = (acc.x - mean) * rs * g2.x + b2.x;
  o2.y = (acc.y - mean) * rs * g2.y + b2.y;
  ((float2*)(hf_ext + (size_t)r * 528))[t] = o2;
  if (t == 0) {
    float sab = 0.f, ss = 0.f, sq = 0.f, mx = -1e30f;
    for (int ch = 0; ch < JC; ++ch) {
      size_t b = ((size_t)ch * NN + r) * 8;
      sab += stats_part[b + 0]; ss += stats_part[b + 1];
      sq += stats_part[b + 2];  mx = fmaxf(mx, stats_part[b + 3]);
    }
    float diag = stats_part[((size_t)(r >> 9) * NN + r) * 8 + 4];
    float L1 = fmaxf(sab, 1e-12f);
    float inv = 1.f / L1;
    float stdv = sqrtf(fmaxf((sq - ss * ss * (1.f / 2048.f)) * (1.f / 2047.f), 0.f)) * inv;
    float* he = hf_ext + (size_t)r * 528;
    he[512] = diag * inv; he[513] = ss * inv; he[514] = stdv; he[515] = mx * inv;
    s_inv = inv;
  }
  if (t < 12) hf_ext[(size_t)r * 528 + 516 + t] = 0.f;
  __syncthreads();
  float inv = s_inv;
  float xv = 0.f;
#pragma unroll
  for (int ch = 0; ch < JC; ++ch) xv += xm_part[((size_t)ch * NN + r) * DXF + t];
  out_xm[(size_t)r * DXF + t] = xv * inv + x[(size_t)r * DXF + t];
}

extern "C" void kernel_launch(void* const* d_in, const int* in_sizes, int n_in,
                              void* d_out, int out_size, void* d_ws, size_t ws_size,
                              hipStream_t stream) {
  (void)in_sizes; (void)n_in; (void)out_size; (void)ws_size;
  const float* h    = (const float*)d_in[0];
  const float* x    = (const float*)d_in[1];
  const float* ln_g = (const float*)d_in[2];
  const float* ln_b = (const float*)d_in[3];
  const float* Wk   = (const float*)d_in[4];
  const float* bk   = (const float*)d_in[5];
  const float* Wq   = (const float*)d_in[6];
  const float* bq   = (const float*)d_in[7];
  const float* Wv   = (const float*)d_in[8];
  const float* bv   = (const float*)d_in[9];
  const float* Wm1  = (const float*)d_in[10];
  const float* bm1  = (const float*)d_in[11];
  const float* Wm2  = (const float*)d_in[12];
  const float* bm2  = (const float*)d_in[13];
  const float* lnf_g = (const float*)d_in[14];
  const float* lnf_b = (const float*)d_in[15];
  const float* Wfc  = (const float*)d_in[16];
  const float* bfc  = (const float*)d_in[17];

  char* wsb = (char*)d_ws;
  size_t off = 0;
  auto alloc = [&](size_t bytes) { char* p = wsb + off; off += (bytes + 255) & ~(size_t)255; return p; };
  float* hn  = (float*)alloc((size_t)NN * FD * 4);
  float* kb  = (float*)alloc((size_t)NN * FD * 4);
  float* qb  = (float*)alloc((size_t)NN * FD * 4);
  float* vb  = (float*)alloc((size_t)NN * FD * 4);
  float* hmp = (float*)alloc((size_t)JC * 8 * NN * 64 * 4);
  float* xmp = (float*)alloc((size_t)JC * NN * DXF * 4);
  float* stp = (float*)alloc((size_t)JC * NN * 8 * 4);
  float* hmf = (float*)alloc((size_t)NN * FD * 4);
  float* hfe = (float*)alloc((size_t)NN * 528 * 4);
  float* wfp = (float*)alloc((size_t)512 * 528 * 4);
  u16* xnB  = (u16*)alloc((size_t)NN * DXF * 2);
  u16* xnTg = (u16*)alloc((size_t)DXF * NN * 2);
  u16* kP   = (u16*)alloc((size_t)8 * NN * 64 * 2);
  u16* qP   = (u16*)alloc((size_t)8 * NN * 64 * 2);
  u16* vPT  = (u16*)alloc((size_t)8 * 64 * NN * 2);
  float* out_hf = (float*)d_out;
  float* out_xm = out_hf + (size_t)NN * FD;

  ln_rows_k<<<NN, 256, 0, stream>>>(h, ln_g, ln_b, hn);
  xn_rows_k<<<NN, 256, 0, stream>>>(x, xnB);
  dim3 gg(32, 8);
  gemm_nt_k<0><<<gg, 256, 0, stream>>>(hn, FD, Wk, FD, bk, nullptr, kb, FD, FD);
  gemm_nt_k<0><<<gg, 256, 0, stream>>>(hn, FD, Wq, FD, bq, nullptr, qb, FD, FD);
  gemm_nt_k<0><<<gg, 256, 0, stream>>>(hn, FD, Wv, FD, bv, nullptr, vb, FD, FD);
  wfc_pad_k<<<(512 * 528 + 255) / 256, 256, 0, stream>>>(Wfc, wfp);
  repack_k<<<NN / 16, 256, 0, stream>>>(kb, qb, vb, xnB, kP, qP, vPT, xnTg);
  dim3 gf(NN / ITI, JC);
  fused_mfma_k<<<gf, 256, 0, stream>>>(kP, qP, vPT, xnB, xnTg, Wm1, bm1, Wm2, bm2,
                                       hmp, xmp, stp);
  epilogue1_k<<<NN, 256, 0, stream>>>(h, x, hmp, xmp, stp, lnf_g, lnf_b, hmf, hfe, out_xm);
  gemm_nt_k<1><<<gg, 256, 0, stream>>>(hfe, 528, wfp, 528, bfc, hmf, out_hf, FD, 528);
}

// Round 4
// 220.101 us; speedup vs baseline: 11.7358x; 1.2935x over previous
//
#include <hip/hip_runtime.h>
#include <math.h>

#define NN 2048
#define FD 512
#define DXF 256
#define JC 8
#define CHKJ (NN/JC)      // 256
#define ITI 16
#define JTW 64
#define NIT (CHKJ/JTW)    // 4

typedef unsigned short u16;
typedef unsigned int u32;
typedef __attribute__((ext_vector_type(8))) short s16x8;
typedef __attribute__((ext_vector_type(4))) float f32x4;

__device__ __forceinline__ f32x4 MFMA16(s16x8 a, s16x8 b, f32x4 c) {
  return __builtin_amdgcn_mfma_f32_16x16x32_bf16(a, b, c, 0, 0, 0);
}
__device__ __forceinline__ float blo(u32 u) { return __uint_as_float(u << 16); }
__device__ __forceinline__ float bhi(u32 u) { return __uint_as_float(u & 0xffff0000u); }
__device__ __forceinline__ float b2f(u16 v) { return __uint_as_float((u32)v << 16); }
__device__ __forceinline__ u16 bf1(float f) {
  u32 u = __float_as_uint(f);
  u += 0x7fffu + ((u >> 16) & 1u);
  return (u16)(u >> 16);
}
__device__ __forceinline__ u32 pkbf(float a, float b) {
  u32 ua = __float_as_uint(a), ub = __float_as_uint(b);
  ua += 0x7fffu + ((ua >> 16) & 1u);
  ub += 0x7fffu + ((ub >> 16) & 1u);
  return (ua >> 16) | (ub & 0xffff0000u);
}

// ---------- layernorm rows of h -> bf16 ----------
__global__ void ln_rows_k(const float* __restrict__ h, const float* __restrict__ g,
                          const float* __restrict__ b, u16* __restrict__ out) {
  int r = blockIdx.x, t = threadIdx.x;
  float2 v = ((const float2*)(h + (size_t)r * FD))[t];
  float2 w = make_float2(v.x + v.y, v.x * v.x + v.y * v.y);
#pragma unroll
  for (int o = 32; o > 0; o >>= 1) { w.x += __shfl_xor(w.x, o); w.y += __shfl_xor(w.y, o); }
  __shared__ float red[4][2];
  if ((t & 63) == 0) { red[t >> 6][0] = w.x; red[t >> 6][1] = w.y; }
  __syncthreads();
  float S  = (red[0][0] + red[1][0]) + (red[2][0] + red[3][0]);
  float SQ = (red[0][1] + red[1][1]) + (red[2][1] + red[3][1]);
  float mean = S * (1.f / FD);
  float var  = SQ * (1.f / FD) - mean * mean;
  float rs = rsqrtf(var + 1e-5f);
  float2 gg = ((const float2*)g)[t], bb = ((const float2*)b)[t];
  float ox = (v.x - mean) * rs * gg.x + bb.x;
  float oy = (v.y - mean) * rs * gg.y + bb.y;
  *(u32*)(out + (size_t)r * FD + 2 * t) = pkbf(ox, oy);
}

// ---------- l1 normalize rows of x -> bf16 ----------
__global__ void xn_rows_k(const float* __restrict__ x, u16* __restrict__ out) {
  int r = blockIdx.x, t = threadIdx.x;
  float v = x[(size_t)r * DXF + t];
  float s = fabsf(v);
#pragma unroll
  for (int o = 32; o > 0; o >>= 1) s += __shfl_xor(s, o);
  __shared__ float red[4];
  if ((t & 63) == 0) red[t >> 6] = s;
  __syncthreads();
  float S = (red[0] + red[1]) + (red[2] + red[3]);
  float inv = 1.f / fmaxf(S, 1e-12f);
  out[(size_t)r * DXF + t] = bf1(v * inv);
}

// ---------- fp32 -> bf16 weight convert ----------
__global__ void cvt_w_k(const float* __restrict__ W, u16* __restrict__ O, int n2) {
  int i = blockIdx.x * 256 + threadIdx.x;
  if (i < n2) {
    float2 v = ((const float2*)W)[i];
    ((u32*)O)[i] = pkbf(v.x, v.y);
  }
}
// Wfc [512][516] -> bf16 [512][544] zero-padded
__global__ void cvt_wfc_k(const float* __restrict__ W, u16* __restrict__ O) {
  int i = blockIdx.x * 256 + threadIdx.x;
  if (i >= 512 * 272) return;
  int r = i / 272, c2 = (i - r * 272) * 2;
  float a = (c2 < 516) ? W[r * 516 + c2] : 0.f;
  float b = (c2 + 1 < 516) ? W[r * 516 + c2 + 1] : 0.f;
  ((u32*)O)[i] = pkbf(a, b);
}

// ---------- transpose xnB [NN][256] -> xnTg [256][NN] ----------
__global__ void xnt_k(const u16* __restrict__ xnB, u16* __restrict__ xnTg) {
  __shared__ u16 tile[16][264];
  int t = threadIdx.x;
  int r0 = blockIdx.x * 16;
#pragma unroll
  for (int s = 0; s < 2; ++s) {
    int c = s * 256 + t;
    int db = c & 31, row = c >> 5;
    *(uint4*)&tile[row][db * 8] = *(const uint4*)(xnB + (size_t)(r0 + row) * DXF + db * 8);
  }
  __syncthreads();
#pragma unroll
  for (int s = 0; s < 2; ++s) {
    int c = s * 256 + t;
    int jb = c & 1, d = c >> 1;
    u32 p[4];
#pragma unroll
    for (int e2 = 0; e2 < 4; ++e2) {
      u16 a = tile[jb * 8 + e2 * 2][d], b = tile[jb * 8 + e2 * 2 + 1][d];
      p[e2] = (u32)a | ((u32)b << 16);
    }
    *(uint4*)(xnTg + (size_t)d * NN + r0 + jb * 8) = make_uint4(p[0], p[1], p[2], p[3]);
  }
}

// ---------- direct-load MFMA NT GEMM ----------
// MODE 0: out = kP/qP planar bf16; MODE 1: out = vPT bf16; MODE 2: fc elu+res fp32;
// MODE 3: raw fp32 out + fused row stats of A (written to stP) when blockIdx.y==0.
template <int MODE>
__global__ __launch_bounds__(256) void mfma_gemm_k(
    const u16* __restrict__ A, int lda, const u16* __restrict__ B, int ldb,
    const float* __restrict__ bias, const float* __restrict__ res,
    void* __restrict__ out, int ldc, int K, float* __restrict__ stP) {
  int t = threadIdx.x, w = t >> 6, lane = t & 63, g = lane >> 4, li = lane & 15;
  int m0 = blockIdx.x * 64 + (w & 1) * 32;
  int n0 = blockIdx.y * 64 + (w >> 1) * 32;
  f32x4 acc[2][2] = {};
  float sab[2] = {0.f, 0.f}, ssu[2] = {0.f, 0.f}, ssq[2] = {0.f, 0.f};
  float smx[2] = {-1e30f, -1e30f};
  const bool do_stats = (MODE == 3) && (blockIdx.y == 0) && ((w >> 1) == 0);
  for (int k0 = 0; k0 < K; k0 += 32) {
    s16x8 a0 = *(const s16x8*)(A + (size_t)(m0 + li) * lda + k0 + g * 8);
    s16x8 a1 = *(const s16x8*)(A + (size_t)(m0 + 16 + li) * lda + k0 + g * 8);
    s16x8 b0 = *(const s16x8*)(B + (size_t)(n0 + li) * ldb + k0 + g * 8);
    s16x8 b1 = *(const s16x8*)(B + (size_t)(n0 + 16 + li) * ldb + k0 + g * 8);
    acc[0][0] = MFMA16(a0, b0, acc[0][0]);
    acc[0][1] = MFMA16(a0, b1, acc[0][1]);
    acc[1][0] = MFMA16(a1, b0, acc[1][0]);
    acc[1][1] = MFMA16(a1, b1, acc[1][1]);
    if (do_stats) {
#pragma unroll
      for (int ms = 0; ms < 2; ++ms) {
        u32 pu[4];
        *(s16x8*)pu = ms ? a1 : a0;
#pragma unroll
        for (int q2 = 0; q2 < 4; ++q2) {
          float x0 = blo(pu[q2]), x1 = bhi(pu[q2]);
          sab[ms] += fabsf(x0) + fabsf(x1);
          ssu[ms] += x0 + x1;
          ssq[ms] += x0 * x0 + x1 * x1;
          smx[ms] = fmaxf(smx[ms], fmaxf(x0, x1));
        }
      }
    }
  }
  if (do_stats) {
#pragma unroll
    for (int off = 16; off < 64; off <<= 1) {
#pragma unroll
      for (int ms = 0; ms < 2; ++ms) {
        sab[ms] += __shfl_xor(sab[ms], off);
        ssu[ms] += __shfl_xor(ssu[ms], off);
        ssq[ms] += __shfl_xor(ssq[ms], off);
        smx[ms] = fmaxf(smx[ms], __shfl_xor(smx[ms], off));
      }
    }
    if (g == 0) {
#pragma unroll
      for (int ms = 0; ms < 2; ++ms) {
        size_t base = (size_t)(m0 + ms * 16 + li) * 8;
        stP[base + 0] = sab[ms]; stP[base + 1] = ssu[ms];
        stP[base + 2] = ssq[ms]; stP[base + 3] = smx[ms];
      }
    }
  }
#pragma unroll
  for (int ms = 0; ms < 2; ++ms)
#pragma unroll
    for (int ns = 0; ns < 2; ++ns) {
      int ncol = n0 + ns * 16 + li;
      float bv = (MODE == 3) ? 0.f : bias[ncol];
      if (MODE == 0) {
#pragma unroll
        for (int r = 0; r < 4; ++r) {
          int i = m0 + ms * 16 + g * 4 + r;
          ((u16*)out)[((size_t)(ncol & 7) * NN + i) * 64 + (ncol >> 3)] =
              bf1(acc[ms][ns][r] + bv);
        }
      } else if (MODE == 1) {
        u16 e[4];
#pragma unroll
        for (int r = 0; r < 4; ++r) e[r] = bf1(acc[ms][ns][r] + bv);
        u32 p0 = (u32)e[0] | ((u32)e[1] << 16);
        u32 p1 = (u32)e[2] | ((u32)e[3] << 16);
        int ib = m0 + ms * 16 + g * 4;
        *(uint2*)((u16*)out + ((size_t)((ncol & 7) * 64 + (ncol >> 3))) * NN + ib) =
            make_uint2(p0, p1);
      } else if (MODE == 2) {
#pragma unroll
        for (int r = 0; r < 4; ++r) {
          int i = m0 + ms * 16 + g * 4 + r;
          float cv = acc[ms][ns][r] + bv;
          cv = (cv > 0.f) ? cv : (expf(cv) - 1.f);
          cv += res[(size_t)i * FD + ncol];
          ((float*)out)[(size_t)i * ldc + ncol] = cv;
        }
      } else {
#pragma unroll
        for (int r = 0; r < 4; ++r) {
          int i = m0 + ms * 16 + g * 4 + r;
          ((float*)out)[(size_t)i * ldc + ncol] = acc[ms][ns][r];
        }
      }
    }
}

// ---------- fused pairwise kernel: scores -> mixing -> softmax -> PV ----------
// grid (128, 8); block 256 = 4 waves, wave w = j-subtile. LDS: P only (16 KB).
__global__ __launch_bounds__(256, 2) void fused_mfma_k(
    const u16* __restrict__ kP, const u16* __restrict__ qP,
    const u16* __restrict__ vPT, const u16* __restrict__ xnB,
    const float* __restrict__ Wm1, const float* __restrict__ bm1,
    const float* __restrict__ Wm2, const float* __restrict__ bm2,
    u16* __restrict__ hmPart, u16* __restrict__ axg, float* __restrict__ stP) {
  __shared__ __align__(16) unsigned char L[16384];  // P[8 hd][16 i][128B swizzled]
  const int t = threadIdx.x, w = t >> 6, lane = t & 63;
  const int g = lane >> 4, li = lane & 15;
  const int i0 = blockIdx.x * ITI, chunk = blockIdx.y;
  const int jL = w * 16 + li;

  float W1[8][9], B1v[8], w2v[8];
#pragma unroll
  for (int o = 0; o < 8; ++o) {
    B1v[o] = bm1[o];
    w2v[o] = Wm2[o];
#pragma unroll
    for (int b3 = 0; b3 < 9; ++b3) W1[o][b3] = Wm1[o * 9 + b3];
  }
  const float b2v = bm2[0];

  f32x4 hmA[2][4];
#pragma unroll
  for (int a = 0; a < 2; ++a)
#pragma unroll
    for (int c = 0; c < 4; ++c) hmA[a][c] = (f32x4)(0.f);

  for (int it = 0; it < NIT; ++it) {
    const int j0 = chunk * CHKJ + it * JTW;
    // ---- phase 1: scores (direct global fragments) ----
    f32x4 accS[9];
#pragma unroll
    for (int a = 0; a < 9; ++a) accS[a] = (f32x4)(0.f);
#pragma unroll
    for (int b = 0; b < 8; ++b)
#pragma unroll
      for (int ks = 0; ks < 2; ++ks) {
        s16x8 af = *(const s16x8*)(kP + ((size_t)b * NN + i0 + li) * 64 + ks * 32 + g * 8);
        s16x8 bf = *(const s16x8*)(qP + ((size_t)b * NN + j0 + jL) * 64 + ks * 32 + g * 8);
        accS[b] = MFMA16(af, bf, accS[b]);
      }
#pragma unroll
    for (int ks = 0; ks < 8; ++ks) {
      s16x8 af = *(const s16x8*)(xnB + (size_t)(i0 + li) * DXF + ks * 32 + g * 8);
      s16x8 bf = *(const s16x8*)(xnB + (size_t)(j0 + jL) * DXF + ks * 32 + g * 8);
      accS[8] = MFMA16(af, bf, accS[8]);
    }
    __syncthreads();  // previous phase-2 P reads complete
    // ---- mixing + softmax + P/axn ----
#pragma unroll
    for (int r = 0; r < 4; ++r) {
      float sb[8];
#pragma unroll
      for (int b = 0; b < 8; ++b) sb[b] = accS[b][r];
      float ax = accS[8][r];
      float m[8];
#pragma unroll
      for (int o = 0; o < 8; ++o) {
        float a = B1v[o] + W1[o][0] * ax;
#pragma unroll
        for (int b = 0; b < 8; ++b) a += W1[o][1 + b] * sb[b];
        m[o] = a;
      }
      float axn = b2v + ax;
#pragma unroll
      for (int o = 0; o < 8; ++o) axn += w2v[o] * m[o];
      const int iL2 = g * 4 + r;
      const int iG = i0 + iL2, jG = j0 + jL;
      axg[(size_t)iG * NN + jG] = bf1(axn);
      if (iG == jG) stP[(size_t)iG * 8 + 4] = axn;
      float mx = m[0];
#pragma unroll
      for (int o = 1; o < 8; ++o) mx = fmaxf(mx, m[o]);
      float es[8], esum = 0.f;
#pragma unroll
      for (int o = 0; o < 8; ++o) { es[o] = __expf(m[o] - mx); esum += es[o]; }
      float inv = 1.f / esum;
      const int base = iL2 * 128 + (((jL >> 3) ^ (iL2 & 7)) << 4) + (jL & 7) * 2;
#pragma unroll
      for (int b = 0; b < 8; ++b)
        *(u16*)(L + b * 2048 + base) = bf1(es[b] * inv);
    }
    __syncthreads();  // P visible
    // ---- phase 2: PV ----
#pragma unroll
    for (int hh = 0; hh < 2; ++hh) {
      const int hd = w * 2 + hh;
#pragma unroll
      for (int kb = 0; kb < 2; ++kb) {
        s16x8 pa = *(const s16x8*)(L + hd * 2048 + li * 128 + (((kb * 4 + g) ^ (li & 7)) << 4));
#pragma unroll
        for (int zt = 0; zt < 4; ++zt) {
          s16x8 vf = *(const s16x8*)(vPT + ((size_t)hd * 64 + zt * 16 + li) * NN +
                                     j0 + kb * 32 + g * 8);
          hmA[hh][zt] = MFMA16(pa, vf, hmA[hh][zt]);
        }
      }
    }
  }
  // ---- write hm partials (bf16) ----
#pragma unroll
  for (int hh = 0; hh < 2; ++hh) {
    const int hd = w * 2 + hh;
#pragma unroll
    for (int zt = 0; zt < 4; ++zt)
#pragma unroll
      for (int r = 0; r < 4; ++r) {
        int i = i0 + g * 4 + r;
        int z = zt * 16 + li;
        hmPart[((size_t)(chunk * 8 + hd) * NN + i) * 64 + z] = bf1(hmA[hh][zt][r]);
      }
  }
}

// ---------- epilogue: combine partials, residual, LN, stats cols, xm out ----------
__global__ void epilogue1_k(
    const float* __restrict__ h, const float* __restrict__ x,
    const u16* __restrict__ hmp, const float* __restrict__ xmf,
    const float* __restrict__ stP,
    const float* __restrict__ lnf_g, const float* __restrict__ lnf_b,
    float* __restrict__ hmf, u16* __restrict__ hfeB, float* __restrict__ out_xm) {
  int r = blockIdx.x, t = threadIdx.x;
  int c0 = 2 * t, c1 = c0 + 1;
  float2 acc = ((const float2*)(h + (size_t)r * FD))[t];
#pragma unroll
  for (int ch = 0; ch < JC; ++ch) {
    acc.x += b2f(hmp[((size_t)(ch * 8 + (c0 & 7)) * NN + r) * 64 + (c0 >> 3)]);
    acc.y += b2f(hmp[((size_t)(ch * 8 + (c1 & 7)) * NN + r) * 64 + (c1 >> 3)]);
  }
  ((float2*)(hmf + (size_t)r * FD))[t] = acc;
  float2 w = make_float2(acc.x + acc.y, acc.x * acc.x + acc.y * acc.y);
#pragma unroll
  for (int o = 32; o > 0; o >>= 1) { w.x += __shfl_xor(w.x, o); w.y += __shfl_xor(w.y, o); }
  __shared__ float red[4][2];
  __shared__ float s_inv;
  if ((t & 63) == 0) { red[t >> 6][0] = w.x; red[t >> 6][1] = w.y; }
  __syncthreads();
  float S  = (red[0][0] + red[1][0]) + (red[2][0] + red[3][0]);
  float SQ = (red[0][1] + red[1][1]) + (red[2][1] + red[3][1]);
  float mean = S * (1.f / FD);
  float var  = SQ * (1.f / FD) - mean * mean;
  float rs = rsqrtf(var + 1e-5f);
  float2 g2 = ((const float2*)lnf_g)[t], b2 = ((const float2*)lnf_b)[t];
  float ox = (acc.x - mean) * rs * g2.x + b2.x;
  float oy = (acc.y - mean) * rs * g2.y + b2.y;
  *(u32*)(hfeB + (size_t)r * 544 + c0) = pkbf(ox, oy);
  if (t == 0) {
    float sab = stP[r * 8 + 0], ssu = stP[r * 8 + 1];
    float ssq = stP[r * 8 + 2], smx = stP[r * 8 + 3];
    float diag = stP[r * 8 + 4];
    float L1 = fmaxf(sab, 1e-12f);
    float inv = 1.f / L1;
    float stdv = sqrtf(fmaxf((ssq - ssu * ssu * (1.f / 2048.f)) * (1.f / 2047.f), 0.f)) * inv;
    u16* he = hfeB + (size_t)r * 544;
    he[512] = bf1(diag * inv); he[513] = bf1(ssu * inv);
    he[514] = bf1(stdv);       he[515] = bf1(smx * inv);
    s_inv = inv;
  }
  if (t < 14) *(u32*)(hfeB + (size_t)r * 544 + 516 + 2 * t) = 0;
  __syncthreads();
  float inv = s_inv;
  out_xm[(size_t)r * DXF + t] = xmf[(size_t)r * DXF + t] * inv + x[(size_t)r * DXF + t];
}

extern "C" void kernel_launch(void* const* d_in, const int* in_sizes, int n_in,
                              void* d_out, int out_size, void* d_ws, size_t ws_size,
                              hipStream_t stream) {
  (void)in_sizes; (void)n_in; (void)out_size; (void)ws_size;
  const float* h    = (const float*)d_in[0];
  const float* x    = (const float*)d_in[1];
  const float* ln_g = (const float*)d_in[2];
  const float* ln_b = (const float*)d_in[3];
  const float* Wk   = (const float*)d_in[4];
  const float* bk   = (const float*)d_in[5];
  const float* Wq   = (const float*)d_in[6];
  const float* bq   = (const float*)d_in[7];
  const float* Wv   = (const float*)d_in[8];
  const float* bv   = (const float*)d_in[9];
  const float* Wm1  = (const float*)d_in[10];
  const float* bm1  = (const float*)d_in[11];
  const float* Wm2  = (const float*)d_in[12];
  const float* bm2  = (const float*)d_in[13];
  const float* lnf_g = (const float*)d_in[14];
  const float* lnf_b = (const float*)d_in[15];
  const float* Wfc  = (const float*)d_in[16];
  const float* bfc  = (const float*)d_in[17];

  char* wsb = (char*)d_ws;
  size_t off = 0;
  auto alloc = [&](size_t bytes) { char* p = wsb + off; off += (bytes + 255) & ~(size_t)255; return p; };
  u16*   hnB  = (u16*)alloc((size_t)NN * FD * 2);
  u16*   wkB  = (u16*)alloc((size_t)FD * FD * 2);
  u16*   wqB  = (u16*)alloc((size_t)FD * FD * 2);
  u16*   wvB  = (u16*)alloc((size_t)FD * FD * 2);
  u16*   wfcB = (u16*)alloc((size_t)512 * 544 * 2);
  u16*   kP   = (u16*)alloc((size_t)8 * NN * 64 * 2);
  u16*   qP   = (u16*)alloc((size_t)8 * NN * 64 * 2);
  u16*   vPT  = (u16*)alloc((size_t)8 * 64 * NN * 2);
  u16*   xnB  = (u16*)alloc((size_t)NN * DXF * 2);
  u16*   xnTg = (u16*)alloc((size_t)DXF * NN * 2);
  u16*   axg  = (u16*)alloc((size_t)NN * NN * 2);
  u16*   hmp  = (u16*)alloc((size_t)JC * 8 * NN * 64 * 2);
  float* xmf  = (float*)alloc((size_t)NN * DXF * 4);
  float* stP  = (float*)alloc((size_t)NN * 8 * 4);
  float* hmf  = (float*)alloc((size_t)NN * FD * 4);
  u16*   hfeB = (u16*)alloc((size_t)NN * 544 * 2);
  float* out_hf = (float*)d_out;
  float* out_xm = out_hf + (size_t)NN * FD;

  ln_rows_k<<<NN, 256, 0, stream>>>(h, ln_g, ln_b, hnB);
  xn_rows_k<<<NN, 256, 0, stream>>>(x, xnB);
  cvt_w_k<<<512, 256, 0, stream>>>(Wk, wkB, FD * FD / 2);
  cvt_w_k<<<512, 256, 0, stream>>>(Wq, wqB, FD * FD / 2);
  cvt_w_k<<<512, 256, 0, stream>>>(Wv, wvB, FD * FD / 2);
  cvt_wfc_k<<<544, 256, 0, stream>>>(Wfc, wfcB);
  xnt_k<<<NN / 16, 256, 0, stream>>>(xnB, xnTg);

  dim3 gp(32, 8);
  mfma_gemm_k<0><<<gp, 256, 0, stream>>>(hnB, FD, wkB, FD, bk, nullptr, kP, 0, FD, nullptr);
  mfma_gemm_k<0><<<gp, 256, 0, stream>>>(hnB, FD, wqB, FD, bq, nullptr, qP, 0, FD, nullptr);
  mfma_gemm_k<1><<<gp, 256, 0, stream>>>(hnB, FD, wvB, FD, bv, nullptr, vPT, 0, FD, nullptr);

  dim3 gf(NN / ITI, JC);
  fused_mfma_k<<<gf, 256, 0, stream>>>(kP, qP, vPT, xnB, Wm1, bm1, Wm2, bm2, hmp, axg, stP);

  dim3 gx(32, 4);
  mfma_gemm_k<3><<<gx, 256, 0, stream>>>(axg, NN, xnTg, NN, nullptr, nullptr, xmf, DXF, NN, stP);

  epilogue1_k<<<NN, 256, 0, stream>>>(h, x, hmp, xmf, stP, lnf_g, lnf_b, hmf, hfeB, out_xm);

  mfma_gemm_k<2><<<gp, 256, 0, stream>>>(hfeB, 544, wfcB, 544, bfc, hmf, out_hf, FD, 544, nullptr);
}